// Round 7
// baseline (326.053 us; speedup 1.0000x reference)
//
#include <hip/hip_runtime.h>
#include <stdint.h>

#define BATCH 2000000
#define NHID  14
#define NWAVE 8                         // 512-thread block: 2 waves/SIMD -> 256 regs/wave
#define ROWS_PER_WAVE 64                // 2 tiles of 32 rows
#define ROWS_PER_BLOCK (NWAVE * ROWS_PER_WAVE)                   // 512
#define NTILES ((BATCH + ROWS_PER_BLOCK - 1) / ROWS_PER_BLOCK)   // 3907
#define NSLOT 120                       // 4 (L0) + 14*8 (hidden) + 4 (out) 32x32x16 A-frags
#define LDS_BYTES (NSLOT * 64 * 16)     // 122880 B -> 1 block/CU

typedef float    v4f  __attribute__((ext_vector_type(4)));
typedef float    v16f __attribute__((ext_vector_type(16)));
typedef _Float16 v8h  __attribute__((ext_vector_type(8)));
typedef __fp16   v2p  __attribute__((ext_vector_type(2)));  // matches cvt_pkrtz return
typedef uint32_t v4u  __attribute__((ext_vector_type(4)));

// 32x32x16 MFMA layouts (gfx950):
//   A[m=lane&31][k=8*(lane>>5)+j]   (j=0..7, v8h)
//   B[k=8*(lane>>5)+j][n=lane&31]
//   C/D[row=(reg&3)+8*(reg>>2)+4*(lane>>5)][col=lane&31]  (v16f)
// k-permutation: K-step t consumes activation FEATURE
//   f(t,hi,j) = 16*t + (j&3) + 8*(j>>2) + 4*hi        (hi = lane>>5)
// chosen so that C reg r of subtile s (feature 32*s + (r&3)+8*(r>>2)+4*hi)
// packs DIRECTLY into next-layer B frags:
//   B[2s+0] half j = relu(C_s[j]),  B[2s+1] half j = relu(C_s[8+j])
// (batch col = lane&31 and hi-group both align -> zero cross-lane ops).
// Bias folded as feature 50 (constant 1.0 propagated via identity row m=50).

__device__ __forceinline__ uint32_t pk(float a, float b) {      // v_cvt_pkrtz_f16_f32
    union { v2p v; uint32_t u; } c;
    c.v = __builtin_amdgcn_cvt_pkrtz(a, b);
    return c.u;
}
__device__ __forceinline__ uint32_t relu_pk(float a, float b) { // pkrtz + v_pk_max_f16
    v2p z = { (__fp16)0.0f, (__fp16)0.0f };
    union { v2p v; uint32_t u; } c;
    c.v = __builtin_amdgcn_cvt_pkrtz(a, b);
    c.v = __builtin_elementwise_max(c.v, z);
    return c.u;
}

__device__ __forceinline__ v16f mfma32(v8h a, v8h b, v16f c) {
    return __builtin_amdgcn_mfma_f32_32x32x16_f16(a, b, c, 0, 0, 0);
}

__device__ __forceinline__ v8h pack_lo(const v16f& c) {   // relu+pack C regs 0..7
    union { v4u u; v8h h; } r;
    r.u.x = relu_pk(c[0], c[1]);
    r.u.y = relu_pk(c[2], c[3]);
    r.u.z = relu_pk(c[4], c[5]);
    r.u.w = relu_pk(c[6], c[7]);
    return r.h;
}
__device__ __forceinline__ v8h pack_hi(const v16f& c) {   // relu+pack C regs 8..15
    union { v4u u; v8h h; } r;
    r.u.x = relu_pk(c[8],  c[9]);
    r.u.y = relu_pk(c[10], c[11]);
    r.u.z = relu_pk(c[12], c[13]);
    r.u.w = relu_pk(c[14], c[15]);
    return r.h;
}

// One hidden layer for one 32-row tile: 8 MFMA_32 (2 indep chains of 4) + 32 VALU.
__device__ __forceinline__ void hidden_tile(const v8h (&A)[8], v8h (&B)[4]) {
    const v16f z = {0.f,0.f,0.f,0.f,0.f,0.f,0.f,0.f,0.f,0.f,0.f,0.f,0.f,0.f,0.f,0.f};
    v16f c0 = mfma32(A[0], B[0], z);        // subtile 0 (features 0-31)
    v16f c1 = mfma32(A[4], B[0], z);        // subtile 1 (features 32-63)
    c0 = mfma32(A[1], B[1], c0);  c1 = mfma32(A[5], B[1], c1);
    c0 = mfma32(A[2], B[2], c0);  c1 = mfma32(A[6], B[2], c1);
    c0 = mfma32(A[3], B[3], c0);  c1 = mfma32(A[7], B[3], c1);
    B[0] = pack_lo(c0);  B[1] = pack_hi(c0);
    B[2] = pack_lo(c1);  B[3] = pack_hi(c1);
}

// Layer 0 for one 32-row tile: dense x loads (all 64 lanes), 4 MFMA_32.
__device__ __forceinline__ void l0_tile(const v8h (&A0)[4],
                                        const float* __restrict__ x,
                                        int r, int hi, v8h (&B)[4]) {
    int rc = r < BATCH ? r : BATCH - 1;
    const float* xp = x + (size_t)rc * 16 + hi * 4;
    v4f xa = *(const v4f*)xp;               // features 4hi..4hi+3
    v4f xb = *(const v4f*)(xp + 8);         // features 8+4hi..11+4hi
    union { v4u u; v8h h; } b0;
    b0.u.x = pk(xa[0], xa[1]);
    b0.u.y = pk(xa[2], xa[3]);
    b0.u.z = pk(xb[0], xb[1]);
    b0.u.w = pk(xb[2], xb[3]);
    union { v4u u; v8h h; } b1;             // t=1: bias-one at f==16 (hi=0, j=0)
    b1.u = (v4u){0u, 0u, 0u, 0u};
    if (hi == 0) b1.u.x = 0x3C00u;          // f16 1.0 in half 0
    const v16f z = {0.f,0.f,0.f,0.f,0.f,0.f,0.f,0.f,0.f,0.f,0.f,0.f,0.f,0.f,0.f,0.f};
    v16f c0 = mfma32(A0[0], b0.h, z);       // sub0, K-step 0
    v16f c1 = mfma32(A0[2], b0.h, z);       // sub1, K-step 0
    c0 = mfma32(A0[1], b1.h, c0);           // sub0, K-step 1 (bias)
    c1 = mfma32(A0[3], b1.h, c1);
    B[0] = pack_lo(c0);  B[1] = pack_hi(c0);
    B[2] = pack_lo(c1);  B[3] = pack_hi(c1);
}

// Output layer for one 32-row tile: 4 chained MFMA_32; rows 0-3 live in
// regs 0..3 of hi=0 lanes (rowlocal=(reg&3)+8*(reg>>2)+4hi).
__device__ __forceinline__ void out_tile(const v8h (&Ao)[4], const v8h (&B)[4],
                                         float* __restrict__ out, int r, int hi) {
    const v16f z = {0.f,0.f,0.f,0.f,0.f,0.f,0.f,0.f,0.f,0.f,0.f,0.f,0.f,0.f,0.f,0.f};
    v16f o = mfma32(Ao[0], B[0], z);
    o = mfma32(Ao[1], B[1], o);
    o = mfma32(Ao[2], B[2], o);
    o = mfma32(Ao[3], B[3], o);
    if (hi == 0 && r < BATCH) {
        v4f v = {o[0], o[1], o[2], o[3]};
        *(v4f*)(out + (size_t)r * 4) = v;   // 16B store per row
    }
}

extern "C" __global__ __launch_bounds__(512, 2)
void mlp16(const float* __restrict__ x,
           const float* __restrict__ W0, const float* __restrict__ b0,
           const float* __restrict__ Wh, const float* __restrict__ bh,
           const float* __restrict__ Wo, const float* __restrict__ bo,
           float* __restrict__ out)
{
    extern __shared__ char smem_raw[];
    v8h* frag = (v8h*)smem_raw;         // [slot][lane], 16 B per lane

    const int tid  = threadIdx.x;
    const int lane = tid & 63;
    const int wv   = tid >> 6;
    const int l31  = lane & 31;
    const int hi   = lane >> 5;

    // ------------- one-time weight staging (bias folded at f==50/16) -------------
    // slot map: 0..3   = L0      (sub = s>>1, t = s&1)
    //           4..115 = hidden  (l = (s-4)>>3, i = (s-4)&7, sub = i>>2, t = i&3)
    //           116..119 = out   (t = s-116)
    for (int s = wv; s < NSLOT; s += NWAVE) {
        float v[8];
        if (s < 4) {                    // layer 0: K=32 (16 real + bias@16)
            int sub = s >> 1, t = s & 1;
            int m = sub * 32 + l31;
            #pragma unroll
            for (int j = 0; j < 8; ++j) {
                int f = 16 * t + (j & 3) + 8 * (j >> 2) + 4 * hi;
                float val = 0.f;
                if (f < 16)       { if (m < 50) val = W0[m * 16 + f]; }
                else if (f == 16) { if (m < 50) val = b0[m]; else if (m == 50) val = 1.f; }
                v[j] = val;
            }
        } else if (s < 116) {           // hidden: bias col 50, identity row 50
            int h = s - 4, l = h >> 3, i = h & 7, sub = i >> 2, t = i & 3;
            int m = sub * 32 + l31;
            const float* W = Wh + l * 2500;
            #pragma unroll
            for (int j = 0; j < 8; ++j) {
                int f = 16 * t + (j & 3) + 8 * (j >> 2) + 4 * hi;
                float val = 0.f;
                if (f < 50)       { if (m < 50) val = W[m * 50 + f]; }
                else if (f == 50) { if (m < 50) val = bh[l * 50 + m]; else if (m == 50) val = 1.f; }
                v[j] = val;
            }
        } else {                        // output: m<4 valid, bias col 50
            int t = s - 116, m = l31;
            #pragma unroll
            for (int j = 0; j < 8; ++j) {
                int f = 16 * t + (j & 3) + 8 * (j >> 2) + 4 * hi;
                float val = 0.f;
                if (m < 4) { if (f < 50) val = Wo[m * 50 + f]; else if (f == 50) val = bo[m]; }
                v[j] = val;
            }
        }
        v8h fv;
        #pragma unroll
        for (int j = 0; j < 8; ++j) fv[j] = (_Float16)v[j];   // RNE
        frag[s * 64 + lane] = fv;
    }
    __syncthreads();                    // only barrier in the kernel

    for (int tile = blockIdx.x; tile < NTILES; tile += gridDim.x) {
        const int rowbase = tile * ROWS_PER_BLOCK + wv * ROWS_PER_WAVE;
        v8h B0[4], B1[4];               // activations for 2x 32-row tiles (regs only)

        // ---- layer 0 ----
        {
            v8h A0[4];
            #pragma unroll
            for (int i = 0; i < 4; ++i) A0[i] = frag[i * 64 + lane];
            l0_tile(A0, x, rowbase +  0 + l31, hi, B0);
            l0_tile(A0, x, rowbase + 32 + l31, hi, B1);
        }

        // ---- 14 hidden layers: 16 MFMA_32 + 64 VALU per wave per layer ----
        for (int l = 0; l < NHID; ++l) {
            v8h A[8];
            const v8h* ab = frag + (4 + l * 8) * 64 + lane;
            #pragma unroll
            for (int i = 0; i < 8; ++i) A[i] = ab[i * 64];    // 8x ds_read_b128
            hidden_tile(A, B0);
            hidden_tile(A, B1);
        }

        // ---- output layer ----
        {
            v8h Ao[4];
            #pragma unroll
            for (int i = 0; i < 4; ++i) Ao[i] = frag[(116 + i) * 64 + lane];
            out_tile(Ao, B0, out, rowbase +  0 + l31, hi);
            out_tile(Ao, B1, out, rowbase + 32 + l31, hi);
        }
    }
}

extern "C" void kernel_launch(void* const* d_in, const int* in_sizes, int n_in,
                              void* d_out, int out_size, void* d_ws, size_t ws_size,
                              hipStream_t stream)
{
    (void)in_sizes; (void)n_in; (void)d_ws; (void)ws_size; (void)out_size;
    (void)hipFuncSetAttribute(reinterpret_cast<const void*>(mlp16),
                              hipFuncAttributeMaxDynamicSharedMemorySize, LDS_BYTES);
    mlp16<<<256, 512, LDS_BYTES, stream>>>(
        (const float*)d_in[0], (const float*)d_in[1], (const float*)d_in[2],
        (const float*)d_in[3], (const float*)d_in[4], (const float*)d_in[5],
        (const float*)d_in[6], (float*)d_out);
}

// Round 9
// 321.851 us; speedup vs baseline: 1.0131x; 1.0131x over previous
//
#include <hip/hip_runtime.h>
#include <stdint.h>

#define BATCH 2000000
#define NHID  14
#define NWAVE 16                        // 1024-thread block: 4 waves/SIMD -> 128 regs/wave
#define ROWS_PER_WAVE 64                // 2 tiles of 32 rows
#define ROWS_PER_BLOCK (NWAVE * ROWS_PER_WAVE)                   // 1024
#define NTILES ((BATCH + ROWS_PER_BLOCK - 1) / ROWS_PER_BLOCK)   // 1954
#define NSLOT 120                       // 4 (L0) + 14*8 (hidden) + 4 (out) 32x32x16 A-frags
#define LDS_BYTES (NSLOT * 64 * 16)     // 122880 B -> 1 block/CU (16 waves/CU)

typedef float    v4f  __attribute__((ext_vector_type(4)));
typedef float    v16f __attribute__((ext_vector_type(16)));
typedef _Float16 v8h  __attribute__((ext_vector_type(8)));
typedef __fp16   v2p  __attribute__((ext_vector_type(2)));  // matches cvt_pkrtz return
typedef uint32_t v4u  __attribute__((ext_vector_type(4)));

// 32x32x16 MFMA layouts (gfx950):
//   A[m=lane&31][k=8*(lane>>5)+j]   (j=0..7, v8h)
//   B[k=8*(lane>>5)+j][n=lane&31]
//   C/D[row=(reg&3)+8*(reg>>2)+4*(lane>>5)][col=lane&31]  (v16f)
// k-permutation: K-step t consumes activation FEATURE
//   f(t,hi,j) = 16*t + (j&3) + 8*(j>>2) + 4*hi        (hi = lane>>5)
// chosen so that C reg r of subtile s (feature 32*s + (r&3)+8*(r>>2)+4*hi)
// packs DIRECTLY into next-layer B frags:
//   B[2s+0] half j = relu(C_s[j]),  B[2s+1] half j = relu(C_s[8+j])
// (batch col = lane&31 and hi-group both align -> zero cross-lane ops).
// Bias folded as feature 50 (constant 1.0 propagated via identity row m=50).

__device__ __forceinline__ uint32_t pk(float a, float b) {      // v_cvt_pkrtz_f16_f32
    union { v2p v; uint32_t u; } c;
    c.v = __builtin_amdgcn_cvt_pkrtz(a, b);
    return c.u;
}
__device__ __forceinline__ uint32_t relu_pk(float a, float b) { // pkrtz + v_pk_max_f16
    v2p z = { (__fp16)0.0f, (__fp16)0.0f };
    union { v2p v; uint32_t u; } c;
    c.v = __builtin_amdgcn_cvt_pkrtz(a, b);
    c.v = __builtin_elementwise_max(c.v, z);
    return c.u;
}

__device__ __forceinline__ v16f mfma32(v8h a, v8h b, v16f c) {
    return __builtin_amdgcn_mfma_f32_32x32x16_f16(a, b, c, 0, 0, 0);
}

__device__ __forceinline__ v8h pack_lo(const v16f& c) {   // relu+pack C regs 0..7
    union { v4u u; v8h h; } r;
    r.u.x = relu_pk(c[0], c[1]);
    r.u.y = relu_pk(c[2], c[3]);
    r.u.z = relu_pk(c[4], c[5]);
    r.u.w = relu_pk(c[6], c[7]);
    return r.h;
}
__device__ __forceinline__ v8h pack_hi(const v16f& c) {   // relu+pack C regs 8..15
    union { v4u u; v8h h; } r;
    r.u.x = relu_pk(c[8],  c[9]);
    r.u.y = relu_pk(c[10], c[11]);
    r.u.z = relu_pk(c[12], c[13]);
    r.u.w = relu_pk(c[14], c[15]);
    return r.h;
}

// One hidden layer for one 32-row tile: 8 MFMA_32 (2 indep chains of 4) + 32 VALU.
__device__ __forceinline__ void hidden_tile(const v8h (&A)[8], v8h (&B)[4]) {
    const v16f z = {0.f,0.f,0.f,0.f,0.f,0.f,0.f,0.f,0.f,0.f,0.f,0.f,0.f,0.f,0.f,0.f};
    v16f c0 = mfma32(A[0], B[0], z);        // subtile 0 (features 0-31)
    v16f c1 = mfma32(A[4], B[0], z);        // subtile 1 (features 32-63)
    c0 = mfma32(A[1], B[1], c0);  c1 = mfma32(A[5], B[1], c1);
    c0 = mfma32(A[2], B[2], c0);  c1 = mfma32(A[6], B[2], c1);
    c0 = mfma32(A[3], B[3], c0);  c1 = mfma32(A[7], B[3], c1);
    B[0] = pack_lo(c0);  B[1] = pack_hi(c0);
    B[2] = pack_lo(c1);  B[3] = pack_hi(c1);
}

// Layer 0 for one 32-row tile: dense x loads (all 64 lanes), 4 MFMA_32.
__device__ __forceinline__ void l0_tile(const v8h (&A0)[4],
                                        const float* __restrict__ x,
                                        int r, int hi, v8h (&B)[4]) {
    int rc = r < BATCH ? r : BATCH - 1;
    const float* xp = x + (size_t)rc * 16 + hi * 4;
    v4f xa = *(const v4f*)xp;               // features 4hi..4hi+3
    v4f xb = *(const v4f*)(xp + 8);         // features 8+4hi..11+4hi
    union { v4u u; v8h h; } b0;
    b0.u.x = pk(xa[0], xa[1]);
    b0.u.y = pk(xa[2], xa[3]);
    b0.u.z = pk(xb[0], xb[1]);
    b0.u.w = pk(xb[2], xb[3]);
    union { v4u u; v8h h; } b1;             // t=1: bias-one at f==16 (hi=0, j=0)
    b1.u = (v4u){0u, 0u, 0u, 0u};
    if (hi == 0) b1.u.x = 0x3C00u;          // f16 1.0 in half 0
    const v16f z = {0.f,0.f,0.f,0.f,0.f,0.f,0.f,0.f,0.f,0.f,0.f,0.f,0.f,0.f,0.f,0.f};
    v16f c0 = mfma32(A0[0], b0.h, z);       // sub0, K-step 0
    v16f c1 = mfma32(A0[2], b0.h, z);       // sub1, K-step 0
    c0 = mfma32(A0[1], b1.h, c0);           // sub0, K-step 1 (bias)
    c1 = mfma32(A0[3], b1.h, c1);
    B[0] = pack_lo(c0);  B[1] = pack_hi(c0);
    B[2] = pack_lo(c1);  B[3] = pack_hi(c1);
}

// Output layer for one 32-row tile: 4 chained MFMA_32; rows 0-3 live in
// regs 0..3 of hi=0 lanes (rowlocal=(reg&3)+8*(reg>>2)+4hi).
__device__ __forceinline__ void out_tile(const v8h (&Ao)[4], const v8h (&B)[4],
                                         float* __restrict__ out, int r, int hi) {
    const v16f z = {0.f,0.f,0.f,0.f,0.f,0.f,0.f,0.f,0.f,0.f,0.f,0.f,0.f,0.f,0.f,0.f};
    v16f o = mfma32(Ao[0], B[0], z);
    o = mfma32(Ao[1], B[1], o);
    o = mfma32(Ao[2], B[2], o);
    o = mfma32(Ao[3], B[3], o);
    if (hi == 0 && r < BATCH) {
        v4f v = {o[0], o[1], o[2], o[3]};
        *(v4f*)(out + (size_t)r * 4) = v;   // 16B store per row
    }
}

extern "C" __global__ __launch_bounds__(1024, 4)
void mlp16(const float* __restrict__ x,
           const float* __restrict__ W0, const float* __restrict__ b0,
           const float* __restrict__ Wh, const float* __restrict__ bh,
           const float* __restrict__ Wo, const float* __restrict__ bo,
           float* __restrict__ out)
{
    extern __shared__ char smem_raw[];
    v8h* frag = (v8h*)smem_raw;         // [slot][lane], 16 B per lane

    const int tid  = threadIdx.x;
    const int lane = tid & 63;
    const int wv   = tid >> 6;
    const int l31  = lane & 31;
    const int hi   = lane >> 5;

    // ------------- one-time weight staging (bias folded at f==50/16) -------------
    // slot map: 0..3   = L0      (sub = s>>1, t = s&1)
    //           4..115 = hidden  (l = (s-4)>>3, i = (s-4)&7, sub = i>>2, t = i&3)
    //           116..119 = out   (t = s-116)
    for (int s = wv; s < NSLOT; s += NWAVE) {
        float v[8];
        if (s < 4) {                    // layer 0: K=32 (16 real + bias@16)
            int sub = s >> 1, t = s & 1;
            int m = sub * 32 + l31;
            #pragma unroll
            for (int j = 0; j < 8; ++j) {
                int f = 16 * t + (j & 3) + 8 * (j >> 2) + 4 * hi;
                float val = 0.f;
                if (f < 16)       { if (m < 50) val = W0[m * 16 + f]; }
                else if (f == 16) { if (m < 50) val = b0[m]; else if (m == 50) val = 1.f; }
                v[j] = val;
            }
        } else if (s < 116) {           // hidden: bias col 50, identity row 50
            int h = s - 4, l = h >> 3, i = h & 7, sub = i >> 2, t = i & 3;
            int m = sub * 32 + l31;
            const float* W = Wh + l * 2500;
            #pragma unroll
            for (int j = 0; j < 8; ++j) {
                int f = 16 * t + (j & 3) + 8 * (j >> 2) + 4 * hi;
                float val = 0.f;
                if (f < 50)       { if (m < 50) val = W[m * 50 + f]; }
                else if (f == 50) { if (m < 50) val = bh[l * 50 + m]; else if (m == 50) val = 1.f; }
                v[j] = val;
            }
        } else {                        // output: m<4 valid, bias col 50
            int t = s - 116, m = l31;
            #pragma unroll
            for (int j = 0; j < 8; ++j) {
                int f = 16 * t + (j & 3) + 8 * (j >> 2) + 4 * hi;
                float val = 0.f;
                if (m < 4) { if (f < 50) val = Wo[m * 50 + f]; else if (f == 50) val = bo[m]; }
                v[j] = val;
            }
        }
        v8h fv;
        #pragma unroll
        for (int j = 0; j < 8; ++j) fv[j] = (_Float16)v[j];   // RNE
        frag[s * 64 + lane] = fv;
    }
    __syncthreads();                    // only barrier in the kernel

    for (int tile = blockIdx.x; tile < NTILES; tile += gridDim.x) {
        const int rowbase = tile * ROWS_PER_BLOCK + wv * ROWS_PER_WAVE;
        v8h B0[4], B1[4];               // activations for 2x 32-row tiles (regs only)

        // ---- layer 0 ----
        {
            v8h A0[4];
            #pragma unroll
            for (int i = 0; i < 4; ++i) A0[i] = frag[i * 64 + lane];
            l0_tile(A0, x, rowbase +  0 + l31, hi, B0);
            l0_tile(A0, x, rowbase + 32 + l31, hi, B1);
        }

        // ---- 14 hidden layers: 16 MFMA_32 + 64 VALU per wave per layer ----
        for (int l = 0; l < NHID; ++l) {
            v8h A[8];
            const v8h* ab = frag + (4 + l * 8) * 64 + lane;
            #pragma unroll
            for (int i = 0; i < 8; ++i) A[i] = ab[i * 64];    // 8x ds_read_b128
            hidden_tile(A, B0);
            hidden_tile(A, B1);
        }

        // ---- output layer ----
        {
            v8h Ao[4];
            #pragma unroll
            for (int i = 0; i < 4; ++i) Ao[i] = frag[(116 + i) * 64 + lane];
            out_tile(Ao, B0, out, rowbase +  0 + l31, hi);
            out_tile(Ao, B1, out, rowbase + 32 + l31, hi);
        }
    }
}

extern "C" void kernel_launch(void* const* d_in, const int* in_sizes, int n_in,
                              void* d_out, int out_size, void* d_ws, size_t ws_size,
                              hipStream_t stream)
{
    (void)in_sizes; (void)n_in; (void)d_ws; (void)ws_size; (void)out_size;
    (void)hipFuncSetAttribute(reinterpret_cast<const void*>(mlp16),
                              hipFuncAttributeMaxDynamicSharedMemorySize, LDS_BYTES);
    mlp16<<<256, 1024, LDS_BYTES, stream>>>(
        (const float*)d_in[0], (const float*)d_in[1], (const float*)d_in[2],
        (const float*)d_in[3], (const float*)d_in[4], (const float*)d_in[5],
        (const float*)d_in[6], (float*)d_out);
}